// Round 3
// 217.266 us; speedup vs baseline: 1.0123x; 1.0123x over previous
//
#include <hip/hip_runtime.h>

#define NB 8192
#define NPTS 1024

// Output layout (flat concat, float32):
//   R: [0, NB*9)           out[b*9 + i*3 + j]
//   t: [NB*9, NB*12)       out[NB*9 + b*3 + i]
//   S: [NB*12, NB*13)      out[NB*12 + b]
//
// Workspace: ws[b*12 + 0..8] = cov (row-major), ws[b*12+9] = |xc|^2,
//            ws[b*12+10] = |yc|^2, [11] = pad (stride 12 floats = 3 float4).

// ---------------- Kernel A: LDS-staged covariance reduction ----------------
// One block (256 threads) per batch. Stage loads are perfectly coalesced
// (each wave instruction covers 1024 contiguous bytes); the stride-3 point
// access happens in LDS, where the 48-B stride maps to a bank-group
// permutation (3t mod 8) -> 2 lanes/bank = conflict-free.
// 8192 blocks at ~24.7 KB LDS each -> 6 resident blocks/CU with continuous
// block turnover (32 generations/CU) to pipeline memory latency.
__global__ __launch_bounds__(256) void cov_kernel(
    const float* __restrict__ x, const float* __restrict__ y,
    const float* __restrict__ mu_x, const float* __restrict__ mu_y,
    float* __restrict__ ws)
{
    __shared__ float4 sx[768];          // 12 KiB: one batch of x
    __shared__ float4 sy[768];          // 12 KiB: one batch of y
    __shared__ float red[4][12];        // cross-wave partials

    const int t = threadIdx.x;
    const int b = blockIdx.x;

    const float4* x4 = (const float4*)(x + (size_t)b * (NPTS * 3));
    const float4* y4 = (const float4*)(y + (size_t)b * (NPTS * 3));

    // Coalesced stage: instruction j has lanes covering float4 [256j, 256j+256).
    const float4 a0 = x4[t], a1 = x4[t + 256], a2 = x4[t + 512];
    const float4 c0 = y4[t], c1 = y4[t + 256], c2 = y4[t + 512];

    // mu loads are block-uniform -> scalar loads; overlap with staging.
    const float mx0 = mu_x[b * 3 + 0], mx1 = mu_x[b * 3 + 1], mx2 = mu_x[b * 3 + 2];
    const float my0 = mu_y[b * 3 + 0], my1 = mu_y[b * 3 + 1], my2 = mu_y[b * 3 + 2];

    sx[t] = a0; sx[t + 256] = a1; sx[t + 512] = a2;
    sy[t] = c0; sy[t + 256] = c1; sy[t + 512] = c2;
    __syncthreads();

    // Thread t owns points 4t..4t+3 -> float4 indices 3t..3t+2.
    const float4 xa = sx[3 * t + 0], xb4 = sx[3 * t + 1], xc4 = sx[3 * t + 2];
    const float4 ya = sy[3 * t + 0], yb4 = sy[3 * t + 1], yc4 = sy[3 * t + 2];

    const float xp[4][3] = {{xa.x, xa.y, xa.z}, {xa.w, xb4.x, xb4.y},
                            {xb4.z, xb4.w, xc4.x}, {xc4.y, xc4.z, xc4.w}};
    const float yp[4][3] = {{ya.x, ya.y, ya.z}, {ya.w, yb4.x, yb4.y},
                            {yb4.z, yb4.w, yc4.x}, {yc4.y, yc4.z, yc4.w}};

    float v[11];
    #pragma unroll
    for (int i = 0; i < 11; ++i) v[i] = 0.0f;

    #pragma unroll
    for (int k = 0; k < 4; ++k) {
        const float xd0 = xp[k][0] - mx0, xd1 = xp[k][1] - mx1, xd2 = xp[k][2] - mx2;
        const float yd0 = yp[k][0] - my0, yd1 = yp[k][1] - my1, yd2 = yp[k][2] - my2;
        v[0] += xd0 * yd0; v[1] += xd0 * yd1; v[2] += xd0 * yd2;
        v[3] += xd1 * yd0; v[4] += xd1 * yd1; v[5] += xd1 * yd2;
        v[6] += xd2 * yd0; v[7] += xd2 * yd1; v[8] += xd2 * yd2;
        v[9]  += xd0 * xd0 + xd1 * xd1 + xd2 * xd2;
        v[10] += yd0 * yd0 + yd1 * yd1 + yd2 * yd2;
    }

    // 64-lane butterfly per wave.
    #pragma unroll
    for (int off = 32; off >= 1; off >>= 1) {
        #pragma unroll
        for (int i = 0; i < 11; ++i) v[i] += __shfl_xor(v[i], off, 64);
    }

    if ((t & 63) == 0) {
        #pragma unroll
        for (int i = 0; i < 11; ++i) red[t >> 6][i] = v[i];
    }
    __syncthreads();

    if (t < 11) {
        ws[(size_t)b * 12 + t] = red[0][t] + red[1][t] + red[2][t] + red[3][t];
    }
}

// ---------------- Kernel B: per-thread polar factor + epilogue ----------------
// One batch per thread. Newton polar iteration is self-correcting, so use the
// raw-rate v_rcp_f32 / v_sqrt_f32 (no IEEE div/sqrt fixup sequences) to cut
// the dependent critical path ~2.5x.
__global__ __launch_bounds__(256) void polar_kernel(
    const float* __restrict__ ws,
    const float* __restrict__ mu_x, const float* __restrict__ mu_y,
    float* __restrict__ out)
{
    const int b = blockIdx.x * 256 + threadIdx.x;

    const float4* w4 = (const float4*)ws + 3 * (size_t)b;
    const float4 w0 = w4[0], w1 = w4[1], w2 = w4[2];

    float Q[9] = {w0.x, w0.y, w0.z, w0.w, w1.x, w1.y, w1.z, w1.w, w2.x};
    const float nxx = w2.y;   // |xc|^2
    const float nyy = w2.z;   // |yc|^2

    // Scaled Newton iteration for the orthogonal polar factor:
    //   Q <- 0.5 * (g*Q + (1/g) * Q^-T),  g = sqrt(||Q^-1||_F / ||Q||_F)
    // Q^-T = cof(Q)/det(Q); converges to U*V^T of the SVD (incl. det<0).
    #pragma unroll
    for (int it = 0; it < 11; ++it) {
        float C[9];
        C[0] = Q[4] * Q[8] - Q[5] * Q[7];
        C[1] = Q[5] * Q[6] - Q[3] * Q[8];
        C[2] = Q[3] * Q[7] - Q[4] * Q[6];
        C[3] = Q[2] * Q[7] - Q[1] * Q[8];
        C[4] = Q[0] * Q[8] - Q[2] * Q[6];
        C[5] = Q[1] * Q[6] - Q[0] * Q[7];
        C[6] = Q[1] * Q[5] - Q[2] * Q[4];
        C[7] = Q[2] * Q[3] - Q[0] * Q[5];
        C[8] = Q[0] * Q[4] - Q[1] * Q[3];
        const float det = Q[0] * C[0] + Q[1] * C[1] + Q[2] * C[2];
        const float invdet = __builtin_amdgcn_rcpf(det);

        float nq = 0.0f, nc = 0.0f;
        #pragma unroll
        for (int i = 0; i < 9; ++i) { nq += Q[i] * Q[i]; nc += C[i] * C[i]; }
        const float g  = __builtin_amdgcn_sqrtf(__builtin_amdgcn_sqrtf(
                             nc * invdet * invdet * __builtin_amdgcn_rcpf(nq)));
        const float hg = 0.5f * g;
        const float hi = 0.5f * invdet * __builtin_amdgcn_rcpf(g);
        #pragma unroll
        for (int i = 0; i < 9; ++i) Q[i] = hg * Q[i] + hi * C[i];
    }

    const float mx0 = mu_x[b * 3 + 0], mx1 = mu_x[b * 3 + 1], mx2 = mu_x[b * 3 + 2];
    const float my0 = mu_y[b * 3 + 0], my1 = mu_y[b * 3 + 1], my2 = mu_y[b * 3 + 2];

    #pragma unroll
    for (int i = 0; i < 9; ++i) out[(size_t)b * 9 + i] = Q[i];

    float* tout = out + (size_t)NB * 9 + (size_t)b * 3;
    tout[0] = my0 - (Q[0] * mx0 + Q[1] * mx1 + Q[2] * mx2);
    tout[1] = my1 - (Q[3] * mx0 + Q[4] * mx1 + Q[5] * mx2);
    tout[2] = my2 - (Q[6] * mx0 + Q[7] * mx1 + Q[8] * mx2);

    out[(size_t)NB * 12 + b] = sqrtf(nyy) / (sqrtf(nxx) + 1e-6f);
}

extern "C" void kernel_launch(void* const* d_in, const int* in_sizes, int n_in,
                              void* d_out, int out_size, void* d_ws, size_t ws_size,
                              hipStream_t stream) {
    const float* x    = (const float*)d_in[0];
    const float* mu_x = (const float*)d_in[1];
    const float* y    = (const float*)d_in[2];
    const float* mu_y = (const float*)d_in[3];
    float* out = (float*)d_out;
    float* ws  = (float*)d_ws;   // needs NB*12*4 = 384 KiB

    cov_kernel<<<dim3(NB), dim3(256), 0, stream>>>(x, y, mu_x, mu_y, ws);
    polar_kernel<<<dim3(NB / 256), dim3(256), 0, stream>>>(ws, mu_x, mu_y, out);
}